// Round 9
// baseline (243.194 us; speedup 1.0000x reference)
//
#include <hip/hip_runtime.h>
#include <math.h>

#define EMBED   64
#define HIDDEN  256
#define SEQ     200
#define MT      13
#define VOCAB   100000

typedef _Float16 f16x8  __attribute__((ext_vector_type(8)));
typedef _Float16 f16x2  __attribute__((ext_vector_type(2)));
typedef float    f32x4  __attribute__((ext_vector_type(4)));
typedef float    f32x2  __attribute__((ext_vector_type(2)));

// ---------------- ws layout (same as R18) ----------------
// [0   , 32K ) fragW16: f16 16*(W0+W2)  [tile 16][kc 2][lane 64] x f16x8
// [32K , 64K ) fragW3 : f16 16*W3       [tile 16][kc 2][lane 64] x f16x8
// [64K , 96K ) fragDt : f16 (W1-W2)^T   [tile 16][kc 2][lane 64] x f16x8
// [96K , 160K) fragB2 : f16 mlp_w1      [tile 16][kc 4][lane 64] x f16x8
// [160K, 160K+6.4M) emb8: fp8(16*user_emb), 64 B/vocab row (L3-resident)
//
// LESSONS: ws re-poisoned per launch (R17, no cross-launch caching); grid-wide
// single-line atomics ~100us (R17); f16 A-frags spill (R19, fp8 frags only);
// cross-phase reg state must stay ~<100 regs (R13/14/16/19 spills).

__global__ void din_setup(const float* __restrict__ attn_w1,
                          const float* __restrict__ mlp_w1,
                          const float* __restrict__ user_emb,
                          _Float16* __restrict__ fragW16,
                          _Float16* __restrict__ fragW3,
                          _Float16* __restrict__ fragDt,
                          _Float16* __restrict__ fragB2,
                          unsigned char* __restrict__ emb8,
                          int do_emb) {
  const int gid = blockIdx.x * 256 + threadIdx.x;
  if (gid < 2048) {                                 // fragW16: f16 16*(W0+W2)
    const int i = gid >> 7, rem = gid & 127, kc = rem >> 6, lane = rem & 63;
    const int n = i * 16 + (lane & 15);
    const int kb = kc * 32 + (lane >> 4) * 8;
    #pragma unroll
    for (int j = 0; j < 8; ++j)
      fragW16[gid * 8 + j] = (_Float16)(16.0f * (attn_w1[(kb + j) * HIDDEN + n]
                                               + attn_w1[(128 + kb + j) * HIDDEN + n]));
  } else if (gid < 4096) {                          // fragW3: f16 16*W3
    const int g = gid - 2048;
    const int i = g >> 7, rem = g & 127, kc = rem >> 6, lane = rem & 63;
    const int n = i * 16 + (lane & 15);
    const int kb = kc * 32 + (lane >> 4) * 8;
    #pragma unroll
    for (int j = 0; j < 8; ++j)
      fragW3[g * 8 + j] = (_Float16)(16.0f * attn_w1[(192 + kb + j) * HIDDEN + n]);
  } else if (gid < 6144) {                          // fragDt: f16 (W1-W2)^T A-frags
    const int g = gid - 4096;
    const int i = g >> 7, rem = g & 127, kc = rem >> 6, lane = rem & 63;
    const int n = i * 16 + (lane & 15);
    const int kb = kc * 32 + (lane >> 4) * 8;
    #pragma unroll
    for (int j = 0; j < 8; ++j)
      fragDt[g * 8 + j] = (_Float16)(attn_w1[(64 + kb + j) * HIDDEN + n]
                                   - attn_w1[(128 + kb + j) * HIDDEN + n]);
  } else if (gid < 10240) {                         // fragB2: mlp_w1 f16 A-frags
    const int g = gid - 6144;
    const int nt = g >> 8, kc = (g >> 6) & 3, lane = g & 63;
    const int n = nt * 16 + (lane & 15);
    const int kb = kc * 32 + (lane >> 4) * 8;
    #pragma unroll
    for (int j = 0; j < 8; ++j)
      fragB2[g * 8 + j] = (_Float16)mlp_w1[(kb + j) * HIDDEN + n];
  } else if (do_emb) {                              // emb8: fp8(16*user_emb)
    const int g = gid - 10240;                      // [0, 800000)
    if (g < VOCAB * EMBED / 8) {
      const int base = g * 8;
      const float4 x = *reinterpret_cast<const float4*>(&user_emb[base]);
      const float4 y = *reinterpret_cast<const float4*>(&user_emb[base + 4]);
      int lo = __builtin_amdgcn_cvt_pk_fp8_f32(16.f * x.x, 16.f * x.y, 0, false);
      lo     = __builtin_amdgcn_cvt_pk_fp8_f32(16.f * x.z, 16.f * x.w, lo, true);
      int hi = __builtin_amdgcn_cvt_pk_fp8_f32(16.f * y.x, 16.f * y.y, 0, false);
      hi     = __builtin_amdgcn_cvt_pk_fp8_f32(16.f * y.z, 16.f * y.w, hi, true);
      *reinterpret_cast<uint2*>(&emb8[base]) = uint2{(unsigned)lo, (unsigned)hi};
    }
  }
}

// ---------------- fused kernel: ONE WAVE per row, ZERO barriers, ZERO LDS ----------------
// R20: the 4-wave block structure spent ~35 of 73 us in barrier-convoy stalls
// (9 __syncthreads/row, lockstep phases). One wave owns a whole row: hist in
// VGPRs + shfl, H B-frags loaded per-lane directly from emb8 (L3), logits in
// lg[13] regs, in-wave softmax, in-wave pooling landing directly in the head's
// B-frag layout. 16 n-tiles processed as 4 sequential groups of 4 (R18's proven
// fp8 merge/c-fold/GEMM per group) to keep the live set ~<105 regs.
// Canary: WRITE_SIZE >= 1 MB => spilled => revert to R18.
__global__ __launch_bounds__(256, 4)
void din_fused_kernel(const int* __restrict__ user_hist,
                      const int* __restrict__ target_item,
                      const float* __restrict__ user_emb,
                      const float* __restrict__ item_emb,
                      const float* __restrict__ attn_b1,
                      const float* __restrict__ attn_w2,
                      const float* __restrict__ mlp_b1,
                      const float* __restrict__ mlp_w2,
                      const float* __restrict__ mlp_b2,
                      const _Float16* __restrict__ fragW16,
                      const _Float16* __restrict__ fragW3,
                      const _Float16* __restrict__ fragDt,
                      const _Float16* __restrict__ fragB2,
                      const unsigned char* __restrict__ emb8,   // may be null
                      float* __restrict__ out,
                      int batch)
{
  const int tid  = threadIdx.x;
  const int lane = tid & 63;
  const int wave = tid >> 6;
  const int m    = lane & 15;
  const int quad = lane >> 4;
  const int row  = blockIdx.x * 4 + wave;
  if (row >= batch) return;                 // no barriers anywhere: safe

  const f16x8* W16v = reinterpret_cast<const f16x8*>(fragW16);
  const f16x8* W3v  = reinterpret_cast<const f16x8*>(fragW3);
  const f16x8* Dtv  = reinterpret_cast<const f16x8*>(fragDt);
  const f16x8* B2v  = reinterpret_cast<const f16x8*>(fragB2);

  // ---- target embedding -> tv0, tv1 (f16x8 per quad) ----
  const int ti = target_item[row];
  const float* tp = item_emb + ti * EMBED + quad * 8;
  const float4 ta = *reinterpret_cast<const float4*>(tp);
  const float4 tb = *reinterpret_cast<const float4*>(tp + 4);
  const float4 tc = *reinterpret_cast<const float4*>(tp + 32);
  const float4 td = *reinterpret_cast<const float4*>(tp + 36);
  union { unsigned u[4]; f16x8 v; } TU0, TU1;
  TU0.u[0] = __builtin_bit_cast(unsigned, __builtin_amdgcn_cvt_pkrtz(ta.x, ta.y));
  TU0.u[1] = __builtin_bit_cast(unsigned, __builtin_amdgcn_cvt_pkrtz(ta.z, ta.w));
  TU0.u[2] = __builtin_bit_cast(unsigned, __builtin_amdgcn_cvt_pkrtz(tb.x, tb.y));
  TU0.u[3] = __builtin_bit_cast(unsigned, __builtin_amdgcn_cvt_pkrtz(tb.z, tb.w));
  TU1.u[0] = __builtin_bit_cast(unsigned, __builtin_amdgcn_cvt_pkrtz(tc.x, tc.y));
  TU1.u[1] = __builtin_bit_cast(unsigned, __builtin_amdgcn_cvt_pkrtz(tc.z, tc.w));
  TU1.u[2] = __builtin_bit_cast(unsigned, __builtin_amdgcn_cvt_pkrtz(td.x, td.y));
  TU1.u[3] = __builtin_bit_cast(unsigned, __builtin_amdgcn_cvt_pkrtz(td.z, td.w));
  const f16x8 tv0 = TU0.v, tv1 = TU1.v;

  // ---- hist -> 4 VGPRs/lane, then vc[13] = hist[st*16 + m] via shfl ----
  const int hb = row * SEQ;
  const int hv0 = user_hist[hb + lane];
  const int hv1 = user_hist[hb + 64 + lane];
  const int hv2 = user_hist[hb + 128 + lane];
  const int hv3 = user_hist[hb + ((192 + lane < SEQ) ? 192 + lane : SEQ - 1)];
  int vc[MT];
  #pragma unroll
  for (int st = 0; st < MT; ++st) {
    const int j = st >> 2;                           // compile-time (unrolled)
    const int src = ((st * 16) & 63) + m;
    const int hvj = (j == 0) ? hv0 : (j == 1) ? hv1 : (j == 2) ? hv2 : hv3;
    vc[st] = __shfl(hvj, src, 64);
  }

  // ---- logits: 4 groups of 4 n-tiles; fp8 merge + c-fold + 13-st MFMA ----
  float lg[MT];
  #pragma unroll
  for (int st = 0; st < MT; ++st) lg[st] = 0.f;

  #pragma unroll 1
  for (int g = 0; g < 4; ++g) {
    long long Aw[4][2];
    f32x4 cn4[4];
    f32x2 w2a[4][2];
    #pragma unroll
    for (int i = 0; i < 4; ++i) {
      const int tile = g * 4 + i;
      #pragma unroll
      for (int c = 0; c < 2; ++c) {
        const f16x8 w16 = W16v[(tile * 2 + c) * 64 + lane];
        const f16x8 w3v = W3v[(tile * 2 + c) * 64 + lane];
        const f16x8 p = w3v * (c ? tv1 : tv0) + w16;     // 16*(W0+W2+W3*t)
        int lo = __builtin_amdgcn_cvt_pk_fp8_f32((float)p[0], (float)p[1], 0, false);
        lo     = __builtin_amdgcn_cvt_pk_fp8_f32((float)p[2], (float)p[3], lo, true);
        int hi = __builtin_amdgcn_cvt_pk_fp8_f32((float)p[4], (float)p[5], 0, false);
        hi     = __builtin_amdgcn_cvt_pk_fp8_f32((float)p[6], (float)p[7], hi, true);
        Aw[i][c] = __builtin_bit_cast(long long, uint2{(unsigned)lo, (unsigned)hi});
      }
      const f16x8 d0 = Dtv[(tile * 2 + 0) * 64 + lane];
      const f16x8 d1 = Dtv[(tile * 2 + 1) * 64 + lane];
      const f32x4 z4 = {0.f, 0.f, 0.f, 0.f};
      f32x4 a = __builtin_amdgcn_mfma_f32_16x16x32_f16(d0, tv0, z4, 0, 0, 0);
      a = __builtin_amdgcn_mfma_f32_16x16x32_f16(d1, tv1, a, 0, 0, 0);
      const int nb = tile * 16 + quad * 4;
      const float4 b1v = *reinterpret_cast<const float4*>(&attn_b1[nb]);
      const float4 w2v = *reinterpret_cast<const float4*>(&attn_w2[nb]);
      cn4[i] = f32x4{256.0f * (b1v.x + a[0]), 256.0f * (b1v.y + a[1]),
                     256.0f * (b1v.z + a[2]), 256.0f * (b1v.w + a[3])};
      w2a[i][0] = f32x2{w2v.x * (1.0f / 256.0f), w2v.y * (1.0f / 256.0f)};
      w2a[i][1] = f32x2{w2v.z * (1.0f / 256.0f), w2v.w * (1.0f / 256.0f)};
    }

    const f32x2 zero2 = {0.f, 0.f};
    #pragma unroll
    for (int st = 0; st < MT; ++st) {
      long long b0, b1;
      if (emb8) {
        const unsigned char* hp = emb8 + (size_t)vc[st] * EMBED + quad * 8;
        b0 = *reinterpret_cast<const long long*>(hp);
        b1 = *reinterpret_cast<const long long*>(hp + 32);
      } else {
        const float* hp = user_emb + (size_t)vc[st] * EMBED + quad * 8;
        const float4 x0 = *reinterpret_cast<const float4*>(hp);
        const float4 x1 = *reinterpret_cast<const float4*>(hp + 4);
        const float4 y0 = *reinterpret_cast<const float4*>(hp + 32);
        const float4 y1 = *reinterpret_cast<const float4*>(hp + 36);
        int lo = __builtin_amdgcn_cvt_pk_fp8_f32(16.f * x0.x, 16.f * x0.y, 0, false);
        lo     = __builtin_amdgcn_cvt_pk_fp8_f32(16.f * x0.z, 16.f * x0.w, lo, true);
        int hi = __builtin_amdgcn_cvt_pk_fp8_f32(16.f * x1.x, 16.f * x1.y, 0, false);
        hi     = __builtin_amdgcn_cvt_pk_fp8_f32(16.f * x1.z, 16.f * x1.w, hi, true);
        b0 = __builtin_bit_cast(long long, uint2{(unsigned)lo, (unsigned)hi});
        lo = __builtin_amdgcn_cvt_pk_fp8_f32(16.f * y0.x, 16.f * y0.y, 0, false);
        lo = __builtin_amdgcn_cvt_pk_fp8_f32(16.f * y0.z, 16.f * y0.w, lo, true);
        hi = __builtin_amdgcn_cvt_pk_fp8_f32(16.f * y1.x, 16.f * y1.y, 0, false);
        hi = __builtin_amdgcn_cvt_pk_fp8_f32(16.f * y1.z, 16.f * y1.w, hi, true);
        b1 = __builtin_bit_cast(long long, uint2{(unsigned)lo, (unsigned)hi});
      }
      f32x2 lgp = {0.f, 0.f};
      #pragma unroll
      for (int i = 0; i < 4; ++i) {
        f32x4 a = __builtin_amdgcn_mfma_f32_16x16x32_fp8_fp8(Aw[i][0], b0, cn4[i], 0, 0, 0);
        a = __builtin_amdgcn_mfma_f32_16x16x32_fp8_fp8(Aw[i][1], b1, a, 0, 0, 0);
        f32x2 a0 = {a[0], a[1]};
        f32x2 a1 = {a[2], a[3]};
        a0 = __builtin_elementwise_max(a0, zero2);
        a1 = __builtin_elementwise_max(a1, zero2);
        lgp += a0 * w2a[i][0];
        lgp += a1 * w2a[i][1];
      }
      float lgs = lgp[0] + lgp[1];
      lgs += __shfl_xor(lgs, 16, 64);
      lgs += __shfl_xor(lgs, 32, 64);
      lg[st] += lgs;
    }
  }

  // ---- in-wave softmax over 13x16 logits (st=12 tail masked) ----
  lg[12] = (m < 8) ? lg[12] : -1e30f;
  float mx = lg[0];
  #pragma unroll
  for (int st = 1; st < MT; ++st) mx = fmaxf(mx, lg[st]);
  mx = fmaxf(mx, __shfl_xor(mx, 1, 64));
  mx = fmaxf(mx, __shfl_xor(mx, 2, 64));
  mx = fmaxf(mx, __shfl_xor(mx, 4, 64));
  mx = fmaxf(mx, __shfl_xor(mx, 8, 64));
  float wsm[MT];
  float tot = 0.f;
  #pragma unroll
  for (int st = 0; st < MT; ++st) { wsm[st] = expf(lg[st] - mx); tot += wsm[st]; }
  tot += __shfl_xor(tot, 1, 64);
  tot += __shfl_xor(tot, 2, 64);
  tot += __shfl_xor(tot, 4, 64);
  tot += __shfl_xor(tot, 8, 64);
  const float inv = 1.0f / tot;
  #pragma unroll
  for (int st = 0; st < MT; ++st) wsm[st] *= inv;

  // ---- in-wave pooling: pk[16] = sum_s w[s]*h16[s][e], e in quad ranges ----
  float pkv[16];
  #pragma unroll
  for (int k = 0; k < 16; ++k) pkv[k] = 0.f;
  #pragma unroll
  for (int st = 0; st < MT; ++st) {
    const float ws = wsm[st];
    if (emb8) {
      const unsigned char* hp = emb8 + (size_t)vc[st] * EMBED + quad * 8;
      const uint2 u0 = *reinterpret_cast<const uint2*>(hp);
      const uint2 u1 = *reinterpret_cast<const uint2*>(hp + 32);
      const f32x2 f0 = __builtin_amdgcn_cvt_pk_f32_fp8((int)u0.x, false);
      const f32x2 f1 = __builtin_amdgcn_cvt_pk_f32_fp8((int)u0.x, true);
      const f32x2 f2 = __builtin_amdgcn_cvt_pk_f32_fp8((int)u0.y, false);
      const f32x2 f3 = __builtin_amdgcn_cvt_pk_f32_fp8((int)u0.y, true);
      const f32x2 f4 = __builtin_amdgcn_cvt_pk_f32_fp8((int)u1.x, false);
      const f32x2 f5 = __builtin_amdgcn_cvt_pk_f32_fp8((int)u1.x, true);
      const f32x2 f6 = __builtin_amdgcn_cvt_pk_f32_fp8((int)u1.y, false);
      const f32x2 f7 = __builtin_amdgcn_cvt_pk_f32_fp8((int)u1.y, true);
      pkv[0]  += ws * f0.x;  pkv[1]  += ws * f0.y;
      pkv[2]  += ws * f1.x;  pkv[3]  += ws * f1.y;
      pkv[4]  += ws * f2.x;  pkv[5]  += ws * f2.y;
      pkv[6]  += ws * f3.x;  pkv[7]  += ws * f3.y;
      pkv[8]  += ws * f4.x;  pkv[9]  += ws * f4.y;
      pkv[10] += ws * f5.x;  pkv[11] += ws * f5.y;
      pkv[12] += ws * f6.x;  pkv[13] += ws * f6.y;
      pkv[14] += ws * f7.x;  pkv[15] += ws * f7.y;
    } else {
      const float* hp = user_emb + (size_t)vc[st] * EMBED + quad * 8;
      const float4 x0 = *reinterpret_cast<const float4*>(hp);
      const float4 x1 = *reinterpret_cast<const float4*>(hp + 4);
      const float4 y0 = *reinterpret_cast<const float4*>(hp + 32);
      const float4 y1 = *reinterpret_cast<const float4*>(hp + 36);
      pkv[0]  += ws * x0.x;  pkv[1]  += ws * x0.y;
      pkv[2]  += ws * x0.z;  pkv[3]  += ws * x0.w;
      pkv[4]  += ws * x1.x;  pkv[5]  += ws * x1.y;
      pkv[6]  += ws * x1.z;  pkv[7]  += ws * x1.w;
      pkv[8]  += ws * y0.x;  pkv[9]  += ws * y0.y;
      pkv[10] += ws * y0.z;  pkv[11] += ws * y0.w;
      pkv[12] += ws * y1.x;  pkv[13] += ws * y1.y;
      pkv[14] += ws * y1.z;  pkv[15] += ws * y1.w;
    }
  }
  // pack to f16 pairs, reduce over m (4 rounds), scale (emb8 path is 16x)
  f16x2 hh[8];
  #pragma unroll
  for (int k = 0; k < 8; ++k)
    hh[k] = __builtin_bit_cast(f16x2, __builtin_amdgcn_cvt_pkrtz(pkv[2 * k], pkv[2 * k + 1]));
  #pragma unroll
  for (int off = 1; off <= 8; off <<= 1) {
    #pragma unroll
    for (int k = 0; k < 8; ++k)
      hh[k] += __builtin_bit_cast(f16x2, __shfl_xor(__builtin_bit_cast(int, hh[k]), off, 64));
  }
  {
    const _Float16 psc = (_Float16)(emb8 ? 0.0625f : 1.0f);
    const f16x2 ps2 = {psc, psc};
    #pragma unroll
    for (int k = 0; k < 8; ++k) hh[k] *= ps2;
  }
  // mb0/mb1: lane (quad q) holds interest[e = q*8..+8] and [32+q*8..+8]
  union { f16x2 h2[4]; f16x8 v; } M0, M1;
  M0.h2[0] = hh[0]; M0.h2[1] = hh[1]; M0.h2[2] = hh[2]; M0.h2[3] = hh[3];
  M1.h2[0] = hh[4]; M1.h2[1] = hh[5]; M1.h2[2] = hh[6]; M1.h2[3] = hh[7];
  const f16x8 mb0 = M0.v, mb1 = M1.v;

  // ---- prediction head: 16 n-tiles, all in this wave ----
  float z = 0.f;
  #pragma unroll 4
  for (int tt = 0; tt < 16; ++tt) {
    const f16x8* B2 = B2v + (tt * 4) * 64 + lane;
    const int nb = tt * 16 + quad * 4;
    const float4 bb = *reinterpret_cast<const float4*>(&mlp_b1[nb]);
    const float4 ww = *reinterpret_cast<const float4*>(&mlp_w2[nb]);
    f32x4 a = {bb.x, bb.y, bb.z, bb.w};
    a = __builtin_amdgcn_mfma_f32_16x16x32_f16(B2[0],   mb0, a, 0, 0, 0);
    a = __builtin_amdgcn_mfma_f32_16x16x32_f16(B2[64],  mb1, a, 0, 0, 0);
    a = __builtin_amdgcn_mfma_f32_16x16x32_f16(B2[128], tv0, a, 0, 0, 0);
    a = __builtin_amdgcn_mfma_f32_16x16x32_f16(B2[192], tv1, a, 0, 0, 0);
    z += fmaxf(a[0], 0.0f) * ww.x;
    z += fmaxf(a[1], 0.0f) * ww.y;
    z += fmaxf(a[2], 0.0f) * ww.z;
    z += fmaxf(a[3], 0.0f) * ww.w;
  }
  z += __shfl_xor(z, 16, 64);
  z += __shfl_xor(z, 32, 64);
  if (lane == 0)
    out[row] = 1.0f / (1.0f + expf(-(z + mlp_b2[0])));
}

extern "C" void kernel_launch(void* const* d_in, const int* in_sizes, int n_in,
                              void* d_out, int out_size, void* d_ws, size_t ws_size,
                              hipStream_t stream) {
  const int*   user_hist   = (const int*)  d_in[0];
  const int*   target_item = (const int*)  d_in[1];
  const float* user_emb    = (const float*)d_in[2];
  const float* item_emb    = (const float*)d_in[3];
  const float* attn_w1     = (const float*)d_in[4];
  const float* attn_b1     = (const float*)d_in[5];
  const float* attn_w2     = (const float*)d_in[6];
  // d_in[7] = attn_b2: constant shift on logits -> cancels in softmax
  const float* mlp_w1      = (const float*)d_in[8];
  const float* mlp_b1      = (const float*)d_in[9];
  const float* mlp_w2      = (const float*)d_in[10];
  const float* mlp_b2      = (const float*)d_in[11];
  float* out = (float*)d_out;

  _Float16* fragW16 = (_Float16*)d_ws;                       // 32 KB
  _Float16* fragW3  = (_Float16*)((char*)d_ws + 32768);      // 32 KB
  _Float16* fragDt  = (_Float16*)((char*)d_ws + 65536);      // 32 KB
  _Float16* fragB2  = (_Float16*)((char*)d_ws + 98304);      // 64 KB
  const size_t emb8_off   = 163840;
  const size_t emb8_bytes = (size_t)VOCAB * EMBED;           // 6.4 MB
  unsigned char* emb8 = nullptr;
  if (ws_size >= emb8_off + emb8_bytes)                      // ws_size call-invariant: capture-safe
    emb8 = (unsigned char*)d_ws + emb8_off;

  const int setup_gids   = 10240 + VOCAB * EMBED / 8;
  const int setup_blocks = (setup_gids + 255) / 256;
  din_setup<<<setup_blocks, 256, 0, stream>>>(
      attn_w1, mlp_w1, user_emb, fragW16, fragW3, fragDt, fragB2,
      emb8 ? emb8 : (unsigned char*)d_ws, emb8 ? 1 : 0);

  const int batch = in_sizes[1];
  din_fused_kernel<<<(batch + 3) / 4, 256, 0, stream>>>(
      user_hist, target_item, user_emb, item_emb,
      attn_b1, attn_w2, mlp_b1, mlp_w2, mlp_b2,
      fragW16, fragW3, fragDt, fragB2, emb8, out, batch);
}

// Round 10
// 165.688 us; speedup vs baseline: 1.4678x; 1.4678x over previous
//
#include <hip/hip_runtime.h>
#include <math.h>

#define EMBED   64
#define HIDDEN  256
#define SEQ     200
#define SEQP    208          // padded to 13 s-tiles of 16
#define MT      13
#define VOCAB   100000

typedef _Float16 f16x8  __attribute__((ext_vector_type(8)));
typedef _Float16 f16x2  __attribute__((ext_vector_type(2)));
typedef float    f32x4  __attribute__((ext_vector_type(4)));
typedef float    f32x2  __attribute__((ext_vector_type(2)));

// ---------------- ws layout ----------------
// [0   , 32K ) fragW16: f16 16*(W0+W2)  [tile 16][kc 2][lane 64] x f16x8
// [32K , 64K ) fragW3 : f16 16*W3       [tile 16][kc 2][lane 64] x f16x8
// [64K , 96K ) fragDt : f16 (W1-W2)^T   [tile 16][kc 2][lane 64] x f16x8
// [96K , 160K) fragB2 : f16 mlp_w1      [tile 16][kc 4][lane 64] x f16x8
// [160K, 160K+6.4M) emb8: fp8(16*user_emb), 64 B/vocab row (L3-resident)
//
// SESSION LEDGER (what is proven on this problem):
//  - BEST: this structure (R18) = 73-75 us fused / ~165 us total.
//  - Register wall: any design holding >~60 arch-VGPRs of cross-phase state
//    spills (R13/R14/R16/R19/R20; WRITE_SIZE is the canary). The arch/AGPR
//    split at >=5 waves/SIMD makes wider tiles infeasible from HIP source.
//  - Occupancy is NOT the lever: 53% occ (R15) == 37% occ (R18) == ~74 us.
//  - Barrier-free one-wave-per-row spills + uncoalesces the gather (R20).
//  - ws is re-poisoned per launch: no cross-launch caching (R17).
//  - Grid-wide single-line completion atomics cost ~100 us (R17).
//  - fp8 A-frags (8 B) over f16 (16 B): same MFMA rate, half the registers (R19).

__global__ void din_setup(const float* __restrict__ attn_w1,
                          const float* __restrict__ mlp_w1,
                          const float* __restrict__ user_emb,
                          _Float16* __restrict__ fragW16,
                          _Float16* __restrict__ fragW3,
                          _Float16* __restrict__ fragDt,
                          _Float16* __restrict__ fragB2,
                          unsigned char* __restrict__ emb8,
                          int do_emb) {
  const int gid = blockIdx.x * 256 + threadIdx.x;
  if (gid < 2048) {                                 // fragW16: f16 16*(W0+W2)
    const int i = gid >> 7, rem = gid & 127, kc = rem >> 6, lane = rem & 63;
    const int n = i * 16 + (lane & 15);
    const int kb = kc * 32 + (lane >> 4) * 8;
    #pragma unroll
    for (int j = 0; j < 8; ++j)
      fragW16[gid * 8 + j] = (_Float16)(16.0f * (attn_w1[(kb + j) * HIDDEN + n]
                                               + attn_w1[(128 + kb + j) * HIDDEN + n]));
  } else if (gid < 4096) {                          // fragW3: f16 16*W3
    const int g = gid - 2048;
    const int i = g >> 7, rem = g & 127, kc = rem >> 6, lane = rem & 63;
    const int n = i * 16 + (lane & 15);
    const int kb = kc * 32 + (lane >> 4) * 8;
    #pragma unroll
    for (int j = 0; j < 8; ++j)
      fragW3[g * 8 + j] = (_Float16)(16.0f * attn_w1[(192 + kb + j) * HIDDEN + n]);
  } else if (gid < 6144) {                          // fragDt: f16 (W1-W2)^T A-frags
    const int g = gid - 4096;
    const int i = g >> 7, rem = g & 127, kc = rem >> 6, lane = rem & 63;
    const int n = i * 16 + (lane & 15);
    const int kb = kc * 32 + (lane >> 4) * 8;
    #pragma unroll
    for (int j = 0; j < 8; ++j)
      fragDt[g * 8 + j] = (_Float16)(attn_w1[(64 + kb + j) * HIDDEN + n]
                                   - attn_w1[(128 + kb + j) * HIDDEN + n]);
  } else if (gid < 10240) {                         // fragB2: mlp_w1 f16 A-frags
    const int g = gid - 6144;
    const int nt = g >> 8, kc = (g >> 6) & 3, lane = g & 63;
    const int n = nt * 16 + (lane & 15);
    const int kb = kc * 32 + (lane >> 4) * 8;
    #pragma unroll
    for (int j = 0; j < 8; ++j)
      fragB2[g * 8 + j] = (_Float16)mlp_w1[(kb + j) * HIDDEN + n];
  } else if (do_emb) {                              // emb8: fp8(16*user_emb)
    const int g = gid - 10240;                      // [0, 800000)
    if (g < VOCAB * EMBED / 8) {
      const int base = g * 8;
      const float4 x = *reinterpret_cast<const float4*>(&user_emb[base]);
      const float4 y = *reinterpret_cast<const float4*>(&user_emb[base + 4]);
      int lo = __builtin_amdgcn_cvt_pk_fp8_f32(16.f * x.x, 16.f * x.y, 0, false);
      lo     = __builtin_amdgcn_cvt_pk_fp8_f32(16.f * x.z, 16.f * x.w, lo, true);
      int hi = __builtin_amdgcn_cvt_pk_fp8_f32(16.f * y.x, 16.f * y.y, 0, false);
      hi     = __builtin_amdgcn_cvt_pk_fp8_f32(16.f * y.z, 16.f * y.w, hi, true);
      *reinterpret_cast<uint2*>(&emb8[base]) = uint2{(unsigned)lo, (unsigned)hi};
    }
  }
}

// ---------------- fused kernel: one block (256 thr, 4 waves) per row ----------------
// R18 structure (verified best):
//  - single-pass 4-tile-per-wave fp8 K=64 GEMM, cn4 as MFMA C-operand
//  - fp8 A-frag merge via f16 pk_fma + cvt chain (8 B frags keep regs low)
//  - conflict-free shfl + f32 lp[4][SEQP] logit path
//  - packed-f16 pooling reduce; strength-reduced gather addressing
//  - launch_bounds(256,4): 128-reg budget; canary WRITE_SIZE >= 1 MB => spill
__global__ __launch_bounds__(256, 4)
void din_fused_kernel(const int* __restrict__ user_hist,
                      const int* __restrict__ target_item,
                      const float* __restrict__ user_emb,
                      const float* __restrict__ item_emb,
                      const float* __restrict__ attn_b1,
                      const float* __restrict__ attn_w2,
                      const float* __restrict__ mlp_b1,
                      const float* __restrict__ mlp_w2,
                      const float* __restrict__ mlp_b2,
                      const _Float16* __restrict__ fragW16,
                      const _Float16* __restrict__ fragW3,
                      const _Float16* __restrict__ fragDt,
                      const _Float16* __restrict__ fragB2,
                      const unsigned char* __restrict__ emb8,   // may be null
                      float* __restrict__ out)
{
  __shared__ __align__(16) uint2 Hf8[MT * 2 * 64];        // 13312 B fp8(16h) B-frags
  __shared__ float lp[4][SEQP];                           // 3328 B f32 logit partials
  __shared__ int   histL[SEQP];                           // 832
  __shared__ float weights[SEQP];                         // 832
  __shared__ __align__(16) _Float16 t16[EMBED];           // 128
  __shared__ __align__(16) _Float16 mi16[EMBED];          // 128
  __shared__ __align__(16) _Float16 ip16[2 * EMBED];      // 256, pooling partials
  __shared__ float red[8];                                // 32
  // total ~18.8 KB

  const int b    = blockIdx.x;
  const int tid  = threadIdx.x;
  const int lane = tid & 63;
  const int wave = tid >> 6;
  const int m    = lane & 15;
  const int quad = lane >> 4;

  // ---- phase 0: target embedding + hist staging ----
  if (tid < EMBED) t16[tid] = (_Float16)item_emb[target_item[b] * EMBED + tid];
  if (tid < SEQP) histL[tid] = (tid < SEQ) ? user_hist[b * SEQ + tid] : 0;
  __syncthreads();

  // ---- phase 1: gather h -> fp8 B-frag LDS; strength-reduced addressing ----
  const int s0  = (wave >> 1) * 16 + m;
  const int kb0 = (wave & 1) * 32 + quad * 8;
  if (emb8) {
    #pragma unroll
    for (int i = 0; i < 7; ++i) {
      const int s = s0 + 32 * i;
      if (s < SEQP) {
        uint2 pv = uint2{0u, 0u};
        if (s < SEQ)
          pv = *reinterpret_cast<const uint2*>(&emb8[histL[s] * EMBED + kb0]);
        Hf8[tid + 256 * i] = pv;
      }
    }
  } else {
    #pragma unroll
    for (int i = 0; i < 7; ++i) {
      const int s = s0 + 32 * i;
      if (s < SEQP) {
        uint2 pv = uint2{0u, 0u};
        if (s < SEQ) {
          const float4* src = reinterpret_cast<const float4*>(&user_emb[histL[s] * EMBED + kb0]);
          const float4 x = src[0], y = src[1];
          int lo = __builtin_amdgcn_cvt_pk_fp8_f32(16.f * x.x, 16.f * x.y, 0, false);
          lo     = __builtin_amdgcn_cvt_pk_fp8_f32(16.f * x.z, 16.f * x.w, lo, true);
          int hi = __builtin_amdgcn_cvt_pk_fp8_f32(16.f * y.x, 16.f * y.y, 0, false);
          hi     = __builtin_amdgcn_cvt_pk_fp8_f32(16.f * y.z, 16.f * y.w, hi, true);
          pv = uint2{(unsigned)lo, (unsigned)hi};
        }
        Hf8[tid + 256 * i] = pv;
      }
    }
  }

  // ---- phase 2: merge + c-fold for this wave's 4 n-tiles (overlaps gather drain) ----
  long long Aw[4][2];
  f32x4 cn4[4];
  float w2n[4][4];
  {
    const f16x8 tv0 = *reinterpret_cast<const f16x8*>(&t16[quad * 8]);
    const f16x8 tv1 = *reinterpret_cast<const f16x8*>(&t16[32 + quad * 8]);
    #pragma unroll
    for (int i = 0; i < 4; ++i) {
      const int tile = wave * 4 + i;
      // merged A-frags: fp8( 16*(W0+W2)[k][n] + 16*W3[k][n]*t[k] ), f16 math
      #pragma unroll
      for (int c = 0; c < 2; ++c) {
        const f16x8 w16 = reinterpret_cast<const f16x8*>(fragW16)[(tile * 2 + c) * 64 + lane];
        const f16x8 w3v = reinterpret_cast<const f16x8*>(fragW3)[(tile * 2 + c) * 64 + lane];
        const f16x8 p = w3v * (c ? tv1 : tv0) + w16;     // v_pk_fma_f16 x4
        int lo = __builtin_amdgcn_cvt_pk_fp8_f32((float)p[0], (float)p[1], 0, false);
        lo     = __builtin_amdgcn_cvt_pk_fp8_f32((float)p[2], (float)p[3], lo, true);
        int hi = __builtin_amdgcn_cvt_pk_fp8_f32((float)p[4], (float)p[5], 0, false);
        hi     = __builtin_amdgcn_cvt_pk_fp8_f32((float)p[6], (float)p[7], hi, true);
        Aw[i][c] = __builtin_bit_cast(long long, uint2{(unsigned)lo, (unsigned)hi});
      }
      // c-fold: c[n] = 256*(b1[n] + sum_k t[k] D[k][n])
      const f16x8 d0 = reinterpret_cast<const f16x8*>(fragDt)[(tile * 2 + 0) * 64 + lane];
      const f16x8 d1 = reinterpret_cast<const f16x8*>(fragDt)[(tile * 2 + 1) * 64 + lane];
      const f32x4 z = {0.f, 0.f, 0.f, 0.f};
      f32x4 acc = __builtin_amdgcn_mfma_f32_16x16x32_f16(d0, tv0, z, 0, 0, 0);
      acc = __builtin_amdgcn_mfma_f32_16x16x32_f16(d1, tv1, acc, 0, 0, 0);
      const int nb = tile * 16 + quad * 4;
      const float4 b1v = *reinterpret_cast<const float4*>(&attn_b1[nb]);
      const float4 w2v = *reinterpret_cast<const float4*>(&attn_w2[nb]);
      cn4[i][0] = 256.0f * (b1v.x + acc[0]);
      cn4[i][1] = 256.0f * (b1v.y + acc[1]);
      cn4[i][2] = 256.0f * (b1v.z + acc[2]);
      cn4[i][3] = 256.0f * (b1v.w + acc[3]);
      w2n[i][0] = w2v.x * (1.0f / 256.0f);
      w2n[i][1] = w2v.y * (1.0f / 256.0f);
      w2n[i][2] = w2v.z * (1.0f / 256.0f);
      w2n[i][3] = w2v.w * (1.0f / 256.0f);
    }
  }
  __syncthreads();   // gather complete before Hf8 reads

  // ---- phase 3: single-pass fp8 K=64 GEMM over 13 s-tiles, 4 n-tiles/wave ----
  #pragma unroll 1
  for (int st = 0; st < MT; ++st) {
    const long long b0 = __builtin_bit_cast(long long, Hf8[(st * 2 + 0) * 64 + lane]);
    const long long b1 = __builtin_bit_cast(long long, Hf8[(st * 2 + 1) * 64 + lane]);
    float lg = 0.f;
    #pragma unroll
    for (int i = 0; i < 4; ++i) {
      f32x4 acc = __builtin_amdgcn_mfma_f32_16x16x32_fp8_fp8(Aw[i][0], b0, cn4[i], 0, 0, 0);
      acc = __builtin_amdgcn_mfma_f32_16x16x32_fp8_fp8(Aw[i][1], b1, acc, 0, 0, 0);
      lg += fmaxf(acc[0], 0.0f) * w2n[i][0] + fmaxf(acc[1], 0.0f) * w2n[i][1]
          + fmaxf(acc[2], 0.0f) * w2n[i][2] + fmaxf(acc[3], 0.0f) * w2n[i][3];
    }
    lg += __shfl_xor(lg, 16, 64);
    lg += __shfl_xor(lg, 32, 64);
    if (lane < 16) lp[wave][st * 16 + lane] = lg;      // conflict-free
  }
  __syncthreads();

  // ---- phase 4: softmax over SEQ ----
  float v = -INFINITY, e = 0.0f;
  if (tid < SEQ)
    v = lp[0][tid] + lp[1][tid] + lp[2][tid] + lp[3][tid];
  {
    float mx = v;
    #pragma unroll
    for (int off = 32; off; off >>= 1) mx = fmaxf(mx, __shfl_xor(mx, off, 64));
    if (lane == 0) red[wave] = mx;
  }
  __syncthreads();
  {
    const float mx = fmaxf(fmaxf(red[0], red[1]), fmaxf(red[2], red[3]));
    e = (tid < SEQ) ? expf(v - mx) : 0.0f;
    float ssum = e;
    #pragma unroll
    for (int off = 32; off; off >>= 1) ssum += __shfl_xor(ssum, off, 64);
    if (lane == 0) red[4 + wave] = ssum;
  }
  __syncthreads();
  {
    const float tot = red[4] + red[5] + red[6] + red[7];
    if (tid < SEQP) weights[tid] = (tid < SEQ) ? e / tot : 0.0f;
  }
  __syncthreads();

  // ---- phase 5: weighted interest pooling; wave -> (kc = w&1, g2 = w>>1) ----
  {
    const int kc = wave & 1, g2 = wave >> 1;
    float pk[8];
    #pragma unroll
    for (int j = 0; j < 8; ++j) pk[j] = 0.f;
    #pragma unroll
    for (int st2 = 0; st2 < 7; ++st2) {
      const int st = g2 + 2 * st2;
      if (st < MT) {
        const float wt = weights[st * 16 + m];
        const uint2 hv = Hf8[(st * 2 + kc) * 64 + lane];
        const f32x2 f0 = __builtin_amdgcn_cvt_pk_f32_fp8((int)hv.x, false);
        const f32x2 f1 = __builtin_amdgcn_cvt_pk_f32_fp8((int)hv.x, true);
        const f32x2 f2 = __builtin_amdgcn_cvt_pk_f32_fp8((int)hv.y, false);
        const f32x2 f3 = __builtin_amdgcn_cvt_pk_f32_fp8((int)hv.y, true);
        pk[0] += wt * f0.x;  pk[1] += wt * f0.y;
        pk[2] += wt * f1.x;  pk[3] += wt * f1.y;
        pk[4] += wt * f2.x;  pk[5] += wt * f2.y;
        pk[6] += wt * f3.x;  pk[7] += wt * f3.y;
      }
    }
    // packed-f16 m-dim reduce (4 regs x 4 rounds)
    f16x2 hh[4];
    #pragma unroll
    for (int k = 0; k < 4; ++k)
      hh[k] = __builtin_bit_cast(f16x2, __builtin_amdgcn_cvt_pkrtz(pk[2 * k], pk[2 * k + 1]));
    #pragma unroll
    for (int off = 1; off <= 8; off <<= 1) {
      #pragma unroll
      for (int k = 0; k < 4; ++k)
        hh[k] += __builtin_bit_cast(f16x2, __shfl_xor(__builtin_bit_cast(int, hh[k]), off, 64));
    }
    if (m == 0) {
      #pragma unroll
      for (int k = 0; k < 4; ++k)
        *reinterpret_cast<f16x2*>(&ip16[g2 * 64 + kc * 32 + quad * 8 + 2 * k]) = hh[k];
    }
  }
  __syncthreads();
  if (tid < EMBED)
    mi16[tid] = (_Float16)(((float)ip16[tid] + (float)ip16[64 + tid]) * 0.0625f);
  __syncthreads();

  // ---- phase 6: prediction head, f16 MFMA; 4 n-tiles/wave ----
  {
    const f16x8 mb0 = *reinterpret_cast<const f16x8*>(&mi16[quad * 8]);
    const f16x8 mb1 = *reinterpret_cast<const f16x8*>(&mi16[32 + quad * 8]);
    const f16x8 tw0 = *reinterpret_cast<const f16x8*>(&t16[quad * 8]);
    const f16x8 tw1 = *reinterpret_cast<const f16x8*>(&t16[32 + quad * 8]);
    float z = 0.f;
    #pragma unroll
    for (int i = 0; i < 4; ++i) {
      const int tt = wave * 4 + i;
      const f16x8* B2 = reinterpret_cast<const f16x8*>(fragB2) + (tt * 4) * 64 + lane;
      const int nb = tt * 16 + quad * 4;
      const float4 bb = *reinterpret_cast<const float4*>(&mlp_b1[nb]);
      const float4 ww = *reinterpret_cast<const float4*>(&mlp_w2[nb]);
      f32x4 acc = {bb.x, bb.y, bb.z, bb.w};
      acc = __builtin_amdgcn_mfma_f32_16x16x32_f16(B2[0],   mb0, acc, 0, 0, 0);
      acc = __builtin_amdgcn_mfma_f32_16x16x32_f16(B2[64],  mb1, acc, 0, 0, 0);
      acc = __builtin_amdgcn_mfma_f32_16x16x32_f16(B2[128], tw0, acc, 0, 0, 0);
      acc = __builtin_amdgcn_mfma_f32_16x16x32_f16(B2[192], tw1, acc, 0, 0, 0);
      z += fmaxf(acc[0], 0.0f) * ww.x;
      z += fmaxf(acc[1], 0.0f) * ww.y;
      z += fmaxf(acc[2], 0.0f) * ww.z;
      z += fmaxf(acc[3], 0.0f) * ww.w;
    }
    z += __shfl_xor(z, 16, 64);
    z += __shfl_xor(z, 32, 64);
    if (lane == 0) red[wave] = z;
  }
  __syncthreads();
  if (tid == 0) {
    const float zz = red[0] + red[1] + red[2] + red[3] + mlp_b2[0];
    out[b] = 1.0f / (1.0f + expf(-zz));
  }
}

extern "C" void kernel_launch(void* const* d_in, const int* in_sizes, int n_in,
                              void* d_out, int out_size, void* d_ws, size_t ws_size,
                              hipStream_t stream) {
  const int*   user_hist   = (const int*)  d_in[0];
  const int*   target_item = (const int*)  d_in[1];
  const float* user_emb    = (const float*)d_in[2];
  const float* item_emb    = (const float*)d_in[3];
  const float* attn_w1     = (const float*)d_in[4];
  const float* attn_b1     = (const float*)d_in[5];
  const float* attn_w2     = (const float*)d_in[6];
  // d_in[7] = attn_b2: constant shift on logits -> cancels in softmax
  const float* mlp_w1      = (const float*)d_in[8];
  const float* mlp_b1      = (const float*)d_in[9];
  const float* mlp_w2      = (const float*)d_in[10];
  const float* mlp_b2      = (const float*)d_in[11];
  float* out = (float*)d_out;

  _Float16* fragW16 = (_Float16*)d_ws;                       // 32 KB
  _Float16* fragW3  = (_Float16*)((char*)d_ws + 32768);      // 32 KB
  _Float16* fragDt  = (_Float16*)((char*)d_ws + 65536);      // 32 KB
  _Float16* fragB2  = (_Float16*)((char*)d_ws + 98304);      // 64 KB
  const size_t emb8_off   = 163840;
  const size_t emb8_bytes = (size_t)VOCAB * EMBED;           // 6.4 MB
  unsigned char* emb8 = nullptr;
  if (ws_size >= emb8_off + emb8_bytes)                      // ws_size call-invariant: capture-safe
    emb8 = (unsigned char*)d_ws + emb8_off;

  const int setup_gids   = 10240 + VOCAB * EMBED / 8;
  const int setup_blocks = (setup_gids + 255) / 256;
  din_setup<<<setup_blocks, 256, 0, stream>>>(
      attn_w1, mlp_w1, user_emb, fragW16, fragW3, fragDt, fragB2,
      emb8 ? emb8 : (unsigned char*)d_ws, emb8 ? 1 : 0);

  const int batch = in_sizes[1];
  din_fused_kernel<<<batch, 256, 0, stream>>>(
      user_hist, target_item, user_emb, item_emb,
      attn_b1, attn_w2, mlp_b1, mlp_w2, mlp_b2,
      fragW16, fragW3, fragDt, fragB2, emb8, out);
}